// Round 1
// baseline (299.496 us; speedup 1.0000x reference)
//
#include <hip/hip_runtime.h>

// PrunedMultiHeadAttention: B=16,N=1024,C=768,H=9,HD=64
// Pipeline: cvt(fp32->fp16) -> GEMM1(qkv+bias,scatter) -> flash attn -> GEMM3(proj+bias)

typedef _Float16 f16x8 __attribute__((ext_vector_type(8)));
typedef _Float16 f16x4 __attribute__((ext_vector_type(4)));
typedef float    f32x4 __attribute__((ext_vector_type(4)));

#define MFMA16(a, b, c) __builtin_amdgcn_mfma_f32_16x16x32_f16(a, b, c, 0, 0, 0)

// ---------------------------------------------------------------- convert
__global__ __launch_bounds__(256) void cvt_f32_f16(const float* __restrict__ src,
                                                   _Float16* __restrict__ dst,
                                                   int nsrc, int ntot) {
  const int i4 = (blockIdx.x * 256 + threadIdx.x) * 4;
  if (i4 >= ntot) return;
  f16x4 h;
  if (i4 + 4 <= nsrc) {
    const float4 v = *(const float4*)(src + i4);
    ((_Float16*)&h)[0] = (_Float16)v.x;
    ((_Float16*)&h)[1] = (_Float16)v.y;
    ((_Float16*)&h)[2] = (_Float16)v.z;
    ((_Float16*)&h)[3] = (_Float16)v.w;
  } else {
    #pragma unroll
    for (int j = 0; j < 4; ++j) {
      const float v = (i4 + j < nsrc) ? src[i4 + j] : 0.f;
      ((_Float16*)&h)[j] = (_Float16)v;
    }
  }
  *(f16x4*)(dst + i4) = h;
}

// ---------------------------------------------------------------- GEMM1: qkv = x @ W^T + b
// A: x16 [16384,768], Bw: w1 padded [1792,768] (rows >=1728 are zero)
// out scattered into Q/K/V [B=16,H=9,N=1024,64] fp16
__global__ __launch_bounds__(256, 2) void gemm1_qkv(const _Float16* __restrict__ A,
                                                    const _Float16* __restrict__ Bw,
                                                    const float* __restrict__ bias,
                                                    _Float16* __restrict__ Qo,
                                                    _Float16* __restrict__ Ko,
                                                    _Float16* __restrict__ Vo) {
  __shared__ __align__(16) _Float16 As[128 * 72];  // +8 pad -> conflict-free b128 reads
  __shared__ __align__(16) _Float16 Bs[128 * 72];
  const int tid = threadIdx.x;
  const int wave = tid >> 6, lane = tid & 63;
  const int lo = lane & 15, hi = lane >> 4;
  const int wm = (wave >> 1) * 64, wn = (wave & 1) * 64;
  const int m0 = blockIdx.x * 128, n0 = blockIdx.y * 128;
  f32x4 acc[4][4] = {};
  for (int k0 = 0; k0 < 768; k0 += 64) {
    __syncthreads();
    #pragma unroll
    for (int it = 0; it < 4; ++it) {
      const int c = it * 256 + tid;
      const int row = c >> 3, cc = c & 7;
      *(uint4*)(As + row * 72 + cc * 8) = *(const uint4*)(A + (m0 + row) * 768 + k0 + cc * 8);
      *(uint4*)(Bs + row * 72 + cc * 8) = *(const uint4*)(Bw + (n0 + row) * 768 + k0 + cc * 8);
    }
    __syncthreads();
    #pragma unroll
    for (int ks = 0; ks < 2; ++ks) {
      f16x8 af[4], bf[4];
      #pragma unroll
      for (int t = 0; t < 4; ++t) {
        af[t] = *(const f16x8*)(As + (wm + t * 16 + lo) * 72 + ks * 32 + hi * 8);
        bf[t] = *(const f16x8*)(Bs + (wn + t * 16 + lo) * 72 + ks * 32 + hi * 8);
      }
      #pragma unroll
      for (int mt = 0; mt < 4; ++mt)
        #pragma unroll
        for (int nt = 0; nt < 4; ++nt)
          acc[mt][nt] = MFMA16(af[mt], bf[nt], acc[mt][nt]);
    }
  }
  // epilogue: C/D layout col=lane&15 (n), row=(lane>>4)*4+i (m)
  const int b = m0 >> 10;            // 128 | 1024 -> batch uniform per block
  const int nrbase = (m0 & 1023) + wm;
  #pragma unroll
  for (int nt = 0; nt < 4; ++nt) {
    const int n = n0 + wn + nt * 16 + lo;
    if (n < 1728) {
      const float bv = bias[n];
      const int t3 = n / 576;
      const int rem = n - t3 * 576;
      const int hh = rem >> 6, d = rem & 63;
      _Float16* dst = (t3 == 0 ? Qo : (t3 == 1 ? Ko : Vo)) + ((b * 9 + hh) << 16) + d;
      #pragma unroll
      for (int mt = 0; mt < 4; ++mt) {
        const int nr = nrbase + mt * 16 + hi * 4;
        #pragma unroll
        for (int i = 0; i < 4; ++i)
          dst[(nr + i) * 64] = (_Float16)(acc[mt][nt][i] + bv);
      }
    }
  }
}

// ---------------------------------------------------------------- flash attention
// Swapped operands: S^T = K·Q^T, O^T = V^T·P^T.  Per block: one (b,h), 64 q rows.
__global__ __launch_bounds__(256, 2) void attn_fused(const _Float16* __restrict__ Qg,
                                                     const _Float16* __restrict__ Kg,
                                                     const _Float16* __restrict__ Vg,
                                                     _Float16* __restrict__ Og) {
  __shared__ __align__(16) _Float16 Qs[64 * 72];
  __shared__ __align__(16) _Float16 Ks[128 * 72];
  __shared__ __align__(16) _Float16 Vts[64 * 128];    // V^T, XOR-swizzled 8-elem chunks
  __shared__ __align__(16) _Float16 Ps[4][16 * 136];  // per-wave P^T staging
  const int tid = threadIdx.x;
  const int wave = tid >> 6, lane = tid & 63;
  const int lo = lane & 15, hi = lane >> 4;
  const int q0 = blockIdx.x * 64;
  const int bh = blockIdx.y;
  const _Float16* Qp = Qg + (bh << 16);
  const _Float16* Kp = Kg + (bh << 16);
  const _Float16* Vp = Vg + (bh << 16);

  #pragma unroll
  for (int it = 0; it < 2; ++it) {
    const int c = it * 256 + tid;
    const int row = c >> 3, cc = c & 7;
    *(uint4*)(Qs + row * 72 + cc * 8) = *(const uint4*)(Qp + (q0 + row) * 64 + cc * 8);
  }
  __syncthreads();
  f16x8 qf[2];  // Q B-fragments, fixed for whole kernel
  #pragma unroll
  for (int ks = 0; ks < 2; ++ks)
    qf[ks] = *(const f16x8*)(Qs + (wave * 16 + lo) * 72 + ks * 32 + hi * 8);

  float m_run = -1e30f, l_run = 0.f;
  f32x4 accO[4] = {};

  for (int t0 = 0; t0 < 1024; t0 += 128) {
    __syncthreads();
    #pragma unroll
    for (int it = 0; it < 4; ++it) {
      const int c = it * 256 + tid;
      const int row = c >> 3, cc = c & 7;
      *(uint4*)(Ks + row * 72 + cc * 8) = *(const uint4*)(Kp + (t0 + row) * 64 + cc * 8);
    }
    // V^T transpose-stage: consecutive lanes -> consecutive d => conflict-free with swizzle
    #pragma unroll
    for (int it = 0; it < 32; ++it) {
      const int c = it * 256 + tid;
      const int d = c & 63, tr = c >> 6;
      Vts[d * 128 + ((((tr >> 3) ^ (d & 15)) << 3) | (tr & 7))] = Vp[(t0 + tr) * 64 + d];
    }
    __syncthreads();

    // S^T [t=128][q=16/wave]: C layout col=lo=q, row=hi*4+i=t
    f32x4 sacc[8] = {};
    #pragma unroll
    for (int tt = 0; tt < 8; ++tt)
      #pragma unroll
      for (int ks = 0; ks < 2; ++ks) {
        const f16x8 kf = *(const f16x8*)(Ks + (tt * 16 + lo) * 72 + ks * 32 + hi * 8);
        sacc[tt] = MFMA16(kf, qf[ks], sacc[tt]);
      }

    float rmax = -1e30f;
    #pragma unroll
    for (int tt = 0; tt < 8; ++tt)
      #pragma unroll
      for (int i = 0; i < 4; ++i) {
        const float s = sacc[tt][i] * 0.125f;  // HD^-0.5
        sacc[tt][i] = s;
        rmax = fmaxf(rmax, s);
      }
    rmax = fmaxf(rmax, __shfl_xor(rmax, 16, 64));
    rmax = fmaxf(rmax, __shfl_xor(rmax, 32, 64));
    const float mnew = fmaxf(m_run, rmax);
    const float alpha = __expf(m_run - mnew);
    float rsum = 0.f;
    #pragma unroll
    for (int tt = 0; tt < 8; ++tt) {
      f16x4 ph;
      #pragma unroll
      for (int i = 0; i < 4; ++i) {
        const float p = __expf(sacc[tt][i] - mnew);
        rsum += p;
        ((_Float16*)&ph)[i] = (_Float16)p;
      }
      *(f16x4*)(&Ps[wave][lo * 136 + tt * 16 + hi * 4]) = ph;
    }
    rsum += __shfl_xor(rsum, 16, 64);
    rsum += __shfl_xor(rsum, 32, 64);
    l_run = l_run * alpha + rsum;
    m_run = mnew;
    #pragma unroll
    for (int dt = 0; dt < 4; ++dt) accO[dt] *= alpha;
    __syncthreads();  // Ps visible (cross-lane within wave)

    // O^T += V^T · P^T : A=V^T (m=d), B=P^T (n=q), K-dim = t (128)
    #pragma unroll
    for (int ks2 = 0; ks2 < 4; ++ks2) {
      const f16x8 pf = *(const f16x8*)(&Ps[wave][lo * 136 + ks2 * 32 + hi * 8]);
      #pragma unroll
      for (int dt = 0; dt < 4; ++dt) {
        const int dd = dt * 16 + lo;
        const f16x8 vf = *(const f16x8*)(Vts + dd * 128 + (((ks2 * 4 + hi) ^ (dd & 15)) << 3));
        accO[dt] = MFMA16(vf, pf, accO[dt]);
      }
    }
  }
  // O^T C layout: col=lo=q, row=hi*4+i=d (+16*dt). Write O [B,N,H*64] fp16.
  const float inv = 1.f / l_run;
  const int qrow = q0 + wave * 16 + lo;
  const int b = bh / 9, hh = bh - (bh / 9) * 9;
  _Float16* op = Og + (((b << 10) + qrow) * 576 + hh * 64);
  #pragma unroll
  for (int dt = 0; dt < 4; ++dt) {
    f16x4 o4;
    #pragma unroll
    for (int i = 0; i < 4; ++i)
      ((_Float16*)&o4)[i] = (_Float16)(accO[dt][i] * inv);
    *(f16x4*)(op + dt * 16 + hi * 4) = o4;
  }
}

// ---------------------------------------------------------------- GEMM3: out = O @ proj_w^T + b (fp32 out)
__global__ __launch_bounds__(256, 2) void gemm3_proj(const _Float16* __restrict__ A,
                                                     const _Float16* __restrict__ Bw,
                                                     const float* __restrict__ bias,
                                                     float* __restrict__ out) {
  __shared__ __align__(16) _Float16 As[128 * 72];
  __shared__ __align__(16) _Float16 Bs[128 * 72];
  const int tid = threadIdx.x;
  const int wave = tid >> 6, lane = tid & 63;
  const int lo = lane & 15, hi = lane >> 4;
  const int wm = (wave >> 1) * 64, wn = (wave & 1) * 64;
  const int m0 = blockIdx.x * 128, n0 = blockIdx.y * 128;
  f32x4 acc[4][4] = {};
  for (int k0 = 0; k0 < 576; k0 += 64) {
    __syncthreads();
    #pragma unroll
    for (int it = 0; it < 4; ++it) {
      const int c = it * 256 + tid;
      const int row = c >> 3, cc = c & 7;
      *(uint4*)(As + row * 72 + cc * 8) = *(const uint4*)(A + (m0 + row) * 576 + k0 + cc * 8);
      *(uint4*)(Bs + row * 72 + cc * 8) = *(const uint4*)(Bw + (n0 + row) * 576 + k0 + cc * 8);
    }
    __syncthreads();
    #pragma unroll
    for (int ks = 0; ks < 2; ++ks) {
      f16x8 af[4], bf[4];
      #pragma unroll
      for (int t = 0; t < 4; ++t) {
        af[t] = *(const f16x8*)(As + (wm + t * 16 + lo) * 72 + ks * 32 + hi * 8);
        bf[t] = *(const f16x8*)(Bs + (wn + t * 16 + lo) * 72 + ks * 32 + hi * 8);
      }
      #pragma unroll
      for (int mt = 0; mt < 4; ++mt)
        #pragma unroll
        for (int nt = 0; nt < 4; ++nt)
          acc[mt][nt] = MFMA16(af[mt], bf[nt], acc[mt][nt]);
    }
  }
  #pragma unroll
  for (int nt = 0; nt < 4; ++nt) {
    const int n = n0 + wn + nt * 16 + lo;
    const float bv = bias[n];
    #pragma unroll
    for (int mt = 0; mt < 4; ++mt) {
      const int mrow = m0 + wm + mt * 16 + hi * 4;
      #pragma unroll
      for (int i = 0; i < 4; ++i)
        out[(mrow + i) * 768 + n] = acc[mt][nt][i] + bv;
    }
  }
}

// ---------------------------------------------------------------- launch
extern "C" void kernel_launch(void* const* d_in, const int* in_sizes, int n_in,
                              void* d_out, int out_size, void* d_ws, size_t ws_size,
                              hipStream_t stream) {
  const float* x      = (const float*)d_in[0];
  const float* qkv_w  = (const float*)d_in[1];
  const float* qkv_b  = (const float*)d_in[2];
  const float* proj_w = (const float*)d_in[3];
  const float* proj_b = (const float*)d_in[4];
  float* out = (float*)d_out;

  // workspace carve (bytes, all 16B aligned); total ~99.5 MB
  char* ws = (char*)d_ws;
  _Float16* x16 = (_Float16*)(ws + 0);          // 16384*768*2    = 25165824
  _Float16* w1p = (_Float16*)(ws + 25165824);   // 1792*768*2     = 2752512 (zero-padded rows 1728..1791)
  _Float16* w2h = (_Float16*)(ws + 27918336);   // 768*576*2      = 884736
  _Float16* Qh  = (_Float16*)(ws + 28803072);   // 16*9*1024*64*2 = 18874368
  _Float16* Kh  = (_Float16*)(ws + 47677440);
  _Float16* Vh  = (_Float16*)(ws + 66551808);
  _Float16* Oh  = (_Float16*)(ws + 85426176);   // [16384,576] fp16

  cvt_f32_f16<<<12288, 256, 0, stream>>>(x, x16, 12582912, 12582912);
  cvt_f32_f16<<<1344, 256, 0, stream>>>(qkv_w, w1p, 1327104, 1376256);
  cvt_f32_f16<<<432, 256, 0, stream>>>(proj_w, w2h, 442368, 442368);
  gemm1_qkv<<<dim3(128, 14), 256, 0, stream>>>(x16, w1p, qkv_b, Qh, Kh, Vh);
  attn_fused<<<dim3(16, 144), 256, 0, stream>>>(Qh, Kh, Vh, Oh);
  gemm3_proj<<<dim3(128, 6), 256, 0, stream>>>(Oh, w2h, proj_b, out);
}

// Round 2
// 271.180 us; speedup vs baseline: 1.1044x; 1.1044x over previous
//
#include <hip/hip_runtime.h>

// PrunedMultiHeadAttention: B=16,N=1024,C=768,H=9,HD=64
// Pipeline: cvt(fp32->fp16) -> GEMM1(qkv+bias, scatter Q/K row-major + V transposed)
//           -> flash attn (Vt staged via b128, conflict-free swizzle) -> GEMM3(proj+bias)

typedef _Float16 f16x8 __attribute__((ext_vector_type(8)));
typedef _Float16 f16x4 __attribute__((ext_vector_type(4)));
typedef float    f32x4 __attribute__((ext_vector_type(4)));

#define MFMA16(a, b, c) __builtin_amdgcn_mfma_f32_16x16x32_f16(a, b, c, 0, 0, 0)

// ---------------------------------------------------------------- convert
__global__ __launch_bounds__(256) void cvt_f32_f16(const float* __restrict__ src,
                                                   _Float16* __restrict__ dst,
                                                   int nsrc, int ntot) {
  const int i4 = (blockIdx.x * 256 + threadIdx.x) * 4;
  if (i4 >= ntot) return;
  f16x4 h;
  if (i4 + 4 <= nsrc) {
    const float4 v = *(const float4*)(src + i4);
    ((_Float16*)&h)[0] = (_Float16)v.x;
    ((_Float16*)&h)[1] = (_Float16)v.y;
    ((_Float16*)&h)[2] = (_Float16)v.z;
    ((_Float16*)&h)[3] = (_Float16)v.w;
  } else {
    #pragma unroll
    for (int j = 0; j < 4; ++j) {
      const float v = (i4 + j < nsrc) ? src[i4 + j] : 0.f;
      ((_Float16*)&h)[j] = (_Float16)v;
    }
  }
  *(f16x4*)(dst + i4) = h;
}

// ---------------------------------------------------------------- GEMM1: qkv = x @ W^T + b
// A: x16 [16384,768], Bw: w1 padded [1792,768] (rows >=1728 are zero)
// Q,K -> [B,H,N,64] row-major; V -> [B,H,64,N] transposed (for attn A-operand staging)
__global__ __launch_bounds__(256, 2) void gemm1_qkv(const _Float16* __restrict__ A,
                                                    const _Float16* __restrict__ Bw,
                                                    const float* __restrict__ bias,
                                                    _Float16* __restrict__ Qo,
                                                    _Float16* __restrict__ Ko,
                                                    _Float16* __restrict__ Vt) {
  __shared__ __align__(16) _Float16 As[128 * 72];  // +8 pad -> conflict-free b128 reads
  __shared__ __align__(16) _Float16 Bs[128 * 72];
  const int tid = threadIdx.x;
  const int wave = tid >> 6, lane = tid & 63;
  const int lo = lane & 15, hi = lane >> 4;
  const int wm = (wave >> 1) * 64, wn = (wave & 1) * 64;
  const int m0 = blockIdx.x * 128, n0 = blockIdx.y * 128;
  f32x4 acc[4][4] = {};
  for (int k0 = 0; k0 < 768; k0 += 64) {
    __syncthreads();
    #pragma unroll
    for (int it = 0; it < 4; ++it) {
      const int c = it * 256 + tid;
      const int row = c >> 3, cc = c & 7;
      *(uint4*)(As + row * 72 + cc * 8) = *(const uint4*)(A + (m0 + row) * 768 + k0 + cc * 8);
      *(uint4*)(Bs + row * 72 + cc * 8) = *(const uint4*)(Bw + (n0 + row) * 768 + k0 + cc * 8);
    }
    __syncthreads();
    #pragma unroll
    for (int ks = 0; ks < 2; ++ks) {
      f16x8 af[4], bf[4];
      #pragma unroll
      for (int t = 0; t < 4; ++t) {
        af[t] = *(const f16x8*)(As + (wm + t * 16 + lo) * 72 + ks * 32 + hi * 8);
        bf[t] = *(const f16x8*)(Bs + (wn + t * 16 + lo) * 72 + ks * 32 + hi * 8);
      }
      #pragma unroll
      for (int mt = 0; mt < 4; ++mt)
        #pragma unroll
        for (int nt = 0; nt < 4; ++nt)
          acc[mt][nt] = MFMA16(af[mt], bf[nt], acc[mt][nt]);
    }
  }
  // epilogue: C/D layout col=lane&15 (n), row=(lane>>4)*4+i (m)
  const int b = m0 >> 10;            // 128 | 1024 -> batch uniform per block
  const int nrbase = (m0 & 1023) + wm;
  #pragma unroll
  for (int nt = 0; nt < 4; ++nt) {
    const int n = n0 + wn + nt * 16 + lo;
    if (n < 1728) {   // wave-uniform: 16-wide n-group never crosses a 576 boundary
      const float bv = bias[n];
      const int t3 = n / 576;
      const int rem = n - t3 * 576;
      const int hh = rem >> 6, d = rem & 63;
      if (t3 == 2) {
        // V transposed: Vt[bh][d][t], t contiguous -> f16x4 stores
        _Float16* dv = Vt + ((b * 9 + hh) << 16) + d * 1024;
        #pragma unroll
        for (int mt = 0; mt < 4; ++mt) {
          const int nr = nrbase + mt * 16 + hi * 4;
          f16x4 h4;
          #pragma unroll
          for (int i = 0; i < 4; ++i)
            ((_Float16*)&h4)[i] = (_Float16)(acc[mt][nt][i] + bv);
          *(f16x4*)(dv + nr) = h4;
        }
      } else {
        _Float16* dst = (t3 == 0 ? Qo : Ko) + ((b * 9 + hh) << 16) + d;
        #pragma unroll
        for (int mt = 0; mt < 4; ++mt) {
          const int nr = nrbase + mt * 16 + hi * 4;
          #pragma unroll
          for (int i = 0; i < 4; ++i)
            dst[(nr + i) * 64] = (_Float16)(acc[mt][nt][i] + bv);
        }
      }
    }
  }
}

// ---------------------------------------------------------------- flash attention
// Swapped operands: S^T = K·Q^T, O^T = V^T·P^T.  Per block: one (b,h), 64 q rows.
// grid (144,16): x = bh so same-bh q-blocks land on the same XCD (id diff % 8 == 0).
__global__ __launch_bounds__(256, 3) void attn_fused(const _Float16* __restrict__ Qg,
                                                     const _Float16* __restrict__ Kg,
                                                     const _Float16* __restrict__ Vtg,
                                                     _Float16* __restrict__ Og) {
  __shared__ __align__(16) _Float16 Ks[128 * 72];      // 18432 B
  __shared__ __align__(16) _Float16 Vts[64 * 136];     // 17408 B, stride-136 swizzle
  __shared__ __align__(16) _Float16 QPs[4][16 * 136];  // 17408 B: Qs (startup) / per-wave Ps
  const int tid = threadIdx.x;
  const int wave = tid >> 6, lane = tid & 63;
  const int lo = lane & 15, hi = lane >> 4;
  const int bh = blockIdx.x;
  const int q0 = blockIdx.y * 64;
  const _Float16* Qp  = Qg + (bh << 16);
  const _Float16* Kp  = Kg + (bh << 16);
  const _Float16* Vtp = Vtg + (bh << 16);

  {  // stage Q (64x64, stride 72) into the QPs region; dead after qf load
    _Float16* Qs = &QPs[0][0];
    #pragma unroll
    for (int it = 0; it < 2; ++it) {
      const int c = it * 256 + tid;
      const int row = c >> 3, cc = c & 7;
      *(uint4*)(Qs + row * 72 + cc * 8) = *(const uint4*)(Qp + (q0 + row) * 64 + cc * 8);
    }
  }
  __syncthreads();
  f16x8 qf[2];  // Q B-fragments, fixed for whole kernel
  #pragma unroll
  for (int ks = 0; ks < 2; ++ks)
    qf[ks] = *(const f16x8*)(&QPs[0][0] + (wave * 16 + lo) * 72 + ks * 32 + hi * 8);

  float m_run = -1e30f, l_run = 0.f;
  f32x4 accO[4] = {};
  const float cs = 0.125f * 1.44269504f;  // HD^-0.5 * log2(e): softmax in exp2 domain

  for (int t0 = 0; t0 < 1024; t0 += 128) {
    __syncthreads();  // all waves done reading prev Ks/Vts (and, iter 0, qf loaded)
    #pragma unroll
    for (int it = 0; it < 4; ++it) {
      const int c = it * 256 + tid;
      const int row = c >> 3, cc = c & 7;
      *(uint4*)(Ks + row * 72 + cc * 8) = *(const uint4*)(Kp + (t0 + row) * 64 + cc * 8);
    }
    #pragma unroll
    for (int it = 0; it < 4; ++it) {
      const int c = it * 256 + tid;
      const int dr = c >> 4, c16 = c & 15;
      *(uint4*)(Vts + dr * 136 + c16 * 8) = *(const uint4*)(Vtp + dr * 1024 + t0 + c16 * 8);
    }
    __syncthreads();

    // S^T [t=128][q=16/wave]: C layout col=lo=q, row=hi*4+i=t
    f32x4 sacc[8] = {};
    #pragma unroll
    for (int tt = 0; tt < 8; ++tt)
      #pragma unroll
      for (int ks = 0; ks < 2; ++ks) {
        const f16x8 kf = *(const f16x8*)(Ks + (tt * 16 + lo) * 72 + ks * 32 + hi * 8);
        sacc[tt] = MFMA16(kf, qf[ks], sacc[tt]);
      }

    float rmax = -1e30f;
    #pragma unroll
    for (int tt = 0; tt < 8; ++tt)
      #pragma unroll
      for (int i = 0; i < 4; ++i)
        rmax = fmaxf(rmax, sacc[tt][i]);
    rmax = fmaxf(rmax, __shfl_xor(rmax, 16, 64));
    rmax = fmaxf(rmax, __shfl_xor(rmax, 32, 64));
    const float mnew = fmaxf(m_run, rmax * cs);
    const float alpha = exp2f(m_run - mnew);
    float rsum = 0.f;
    #pragma unroll
    for (int tt = 0; tt < 8; ++tt) {
      f16x4 ph;
      #pragma unroll
      for (int i = 0; i < 4; ++i) {
        const float p = exp2f(fmaf(sacc[tt][i], cs, -mnew));
        rsum += p;
        ((_Float16*)&ph)[i] = (_Float16)p;
      }
      *(f16x4*)(&QPs[wave][lo * 136 + tt * 16 + hi * 4]) = ph;
    }
    rsum += __shfl_xor(rsum, 16, 64);
    rsum += __shfl_xor(rsum, 32, 64);
    l_run = l_run * alpha + rsum;
    m_run = mnew;
    #pragma unroll
    for (int dt = 0; dt < 4; ++dt) accO[dt] *= alpha;

    // O^T += V^T · P^T (Ps wave-private: no barrier needed)
    #pragma unroll
    for (int ks2 = 0; ks2 < 4; ++ks2) {
      const f16x8 pf = *(const f16x8*)(&QPs[wave][lo * 136 + ks2 * 32 + hi * 8]);
      #pragma unroll
      for (int dt = 0; dt < 4; ++dt) {
        const f16x8 vf = *(const f16x8*)(Vts + (dt * 16 + lo) * 136 + ks2 * 32 + hi * 8);
        accO[dt] = MFMA16(vf, pf, accO[dt]);
      }
    }
  }
  // O^T C layout: col=lo=q, row=hi*4+i=d (+16*dt). Write O [B,N,H*64] fp16.
  const float inv = 1.f / l_run;
  const int qrow = q0 + wave * 16 + lo;
  const int b = bh / 9, hh = bh - (bh / 9) * 9;
  _Float16* op = Og + (((b << 10) + qrow) * 576 + hh * 64);
  #pragma unroll
  for (int dt = 0; dt < 4; ++dt) {
    f16x4 o4;
    #pragma unroll
    for (int i = 0; i < 4; ++i)
      ((_Float16*)&o4)[i] = (_Float16)(accO[dt][i] * inv);
    *(f16x4*)(op + dt * 16 + hi * 4) = o4;
  }
}

// ---------------------------------------------------------------- GEMM3: out = O @ proj_w^T + b (fp32 out)
__global__ __launch_bounds__(256, 2) void gemm3_proj(const _Float16* __restrict__ A,
                                                     const _Float16* __restrict__ Bw,
                                                     const float* __restrict__ bias,
                                                     float* __restrict__ out) {
  __shared__ __align__(16) _Float16 As[128 * 72];
  __shared__ __align__(16) _Float16 Bs[128 * 72];
  const int tid = threadIdx.x;
  const int wave = tid >> 6, lane = tid & 63;
  const int lo = lane & 15, hi = lane >> 4;
  const int wm = (wave >> 1) * 64, wn = (wave & 1) * 64;
  const int m0 = blockIdx.x * 128, n0 = blockIdx.y * 128;
  f32x4 acc[4][4] = {};
  for (int k0 = 0; k0 < 576; k0 += 64) {
    __syncthreads();
    #pragma unroll
    for (int it = 0; it < 4; ++it) {
      const int c = it * 256 + tid;
      const int row = c >> 3, cc = c & 7;
      *(uint4*)(As + row * 72 + cc * 8) = *(const uint4*)(A + (m0 + row) * 576 + k0 + cc * 8);
      *(uint4*)(Bs + row * 72 + cc * 8) = *(const uint4*)(Bw + (n0 + row) * 576 + k0 + cc * 8);
    }
    __syncthreads();
    #pragma unroll
    for (int ks = 0; ks < 2; ++ks) {
      f16x8 af[4], bf[4];
      #pragma unroll
      for (int t = 0; t < 4; ++t) {
        af[t] = *(const f16x8*)(As + (wm + t * 16 + lo) * 72 + ks * 32 + hi * 8);
        bf[t] = *(const f16x8*)(Bs + (wn + t * 16 + lo) * 72 + ks * 32 + hi * 8);
      }
      #pragma unroll
      for (int mt = 0; mt < 4; ++mt)
        #pragma unroll
        for (int nt = 0; nt < 4; ++nt)
          acc[mt][nt] = MFMA16(af[mt], bf[nt], acc[mt][nt]);
    }
  }
  #pragma unroll
  for (int nt = 0; nt < 4; ++nt) {
    const int n = n0 + wn + nt * 16 + lo;
    const float bv = bias[n];
    #pragma unroll
    for (int mt = 0; mt < 4; ++mt) {
      const int mrow = m0 + wm + mt * 16 + hi * 4;
      #pragma unroll
      for (int i = 0; i < 4; ++i)
        out[(mrow + i) * 768 + n] = acc[mt][nt][i] + bv;
    }
  }
}

// ---------------------------------------------------------------- launch
extern "C" void kernel_launch(void* const* d_in, const int* in_sizes, int n_in,
                              void* d_out, int out_size, void* d_ws, size_t ws_size,
                              hipStream_t stream) {
  const float* x      = (const float*)d_in[0];
  const float* qkv_w  = (const float*)d_in[1];
  const float* qkv_b  = (const float*)d_in[2];
  const float* proj_w = (const float*)d_in[3];
  const float* proj_b = (const float*)d_in[4];
  float* out = (float*)d_out;

  // workspace carve (bytes, all 16B aligned); total ~99.5 MB
  char* ws = (char*)d_ws;
  _Float16* x16 = (_Float16*)(ws + 0);          // 16384*768*2    = 25165824
  _Float16* w1p = (_Float16*)(ws + 25165824);   // 1792*768*2     = 2752512 (zero-padded rows 1728..1791)
  _Float16* w2h = (_Float16*)(ws + 27918336);   // 768*576*2      = 884736
  _Float16* Qh  = (_Float16*)(ws + 28803072);   // 16*9*1024*64*2 = 18874368
  _Float16* Kh  = (_Float16*)(ws + 47677440);
  _Float16* Vth = (_Float16*)(ws + 66551808);   // V transposed [bh][64][1024]
  _Float16* Oh  = (_Float16*)(ws + 85426176);   // [16384,576] fp16

  cvt_f32_f16<<<12288, 256, 0, stream>>>(x, x16, 12582912, 12582912);
  cvt_f32_f16<<<1344, 256, 0, stream>>>(qkv_w, w1p, 1327104, 1376256);
  cvt_f32_f16<<<432, 256, 0, stream>>>(proj_w, w2h, 442368, 442368);
  gemm1_qkv<<<dim3(128, 14), 256, 0, stream>>>(x16, w1p, qkv_b, Qh, Kh, Vth);
  attn_fused<<<dim3(144, 16), 256, 0, stream>>>(Qh, Kh, Vth, Oh);
  gemm3_proj<<<dim3(128, 6), 256, 0, stream>>>(Oh, w2h, proj_b, out);
}

// Round 4
// 257.158 us; speedup vs baseline: 1.1646x; 1.0545x over previous
//
#include <hip/hip_runtime.h>

// PrunedMultiHeadAttention: B=16,N=1024,C=768,H=9,HD=64
// All f16 operand matrices live in global memory XOR-chunk-swizzled:
//   within each aligned group of 8 16B-chunks (64 elems = one BK tile),
//   logical chunk c of row r is stored at position (c & ~7) | ((c ^ r) & 7).
// This makes global_load_lds (lane-linear DMA into unpadded stride-64/128 LDS)
// conflict-free on the MFMA b128 fragment reads (group = (4ks+hi)^(lo&7)).

typedef _Float16 f16x8 __attribute__((ext_vector_type(8)));
typedef _Float16 f16x4 __attribute__((ext_vector_type(4)));
typedef __fp16   h16x2 __attribute__((ext_vector_type(2)));  // cvt_pkrtz result type
typedef float    f32x4 __attribute__((ext_vector_type(4)));

#define MFMA16(a, b, c) __builtin_amdgcn_mfma_f32_16x16x32_f16(a, b, c, 0, 0, 0)

// async global->LDS DMA, 16B/lane; LDS dest = wave-uniform base + lane*16
__device__ __forceinline__ void gld16(const _Float16* g, _Float16* l) {
  __builtin_amdgcn_global_load_lds((const __attribute__((address_space(1))) void*)g,
                                   (__attribute__((address_space(3))) void*)l, 16, 0, 0);
}

// ---------------------------------------------------------------- convert + swizzle
// fp32 row-major [rows_src x (cpr*8)] -> fp16 swizzled [rows_dst x (cpr*8)], zero-pad rows >= rows_src
__global__ __launch_bounds__(256) void cvt_swz(const float* __restrict__ src,
                                               _Float16* __restrict__ dst,
                                               int rows_src, int cpr, int total) {
  const int g = blockIdx.x * 256 + threadIdx.x;
  if (g >= total) return;
  const int row = g / cpr;
  const int c = g - row * cpr;
  const int L = cpr * 8;
  const int pos = (c & ~7) | ((c ^ row) & 7);
  union { f16x8 v; h16x2 h[4]; } u;
  if (row < rows_src) {
    const float4 a = *(const float4*)(src + row * L + c * 8);
    const float4 b = *(const float4*)(src + row * L + c * 8 + 4);
    u.h[0] = __builtin_amdgcn_cvt_pkrtz(a.x, a.y);
    u.h[1] = __builtin_amdgcn_cvt_pkrtz(a.z, a.w);
    u.h[2] = __builtin_amdgcn_cvt_pkrtz(b.x, b.y);
    u.h[3] = __builtin_amdgcn_cvt_pkrtz(b.z, b.w);
  } else {
    u.v = (f16x8){};
  }
  *(f16x8*)(dst + row * L + pos * 8) = u.v;
}

// ---------------------------------------------------------------- GEMM1: qkv = x @ W^T + b
// A: x16 swz [16384,768], Bw: w1 swz padded [1792,768] (rows >=1728 zero)
// Q -> [B,H,N,64] plain; K -> [B,H,N,64] swizzled; V -> [B,H,64,N] transposed+swizzled
__global__ __launch_bounds__(256, 4) void gemm1_qkv(const _Float16* __restrict__ A,
                                                    const _Float16* __restrict__ Bw,
                                                    const float* __restrict__ bias,
                                                    _Float16* __restrict__ Qo,
                                                    _Float16* __restrict__ Ko,
                                                    _Float16* __restrict__ Vt) {
  __shared__ __align__(16) _Float16 As[128 * 64];
  __shared__ __align__(16) _Float16 Bs[128 * 64];
  const int tid = threadIdx.x;
  const int wave = tid >> 6, lane = tid & 63;
  const int lo = lane & 15, hi = lane >> 4;
  const int wm = (wave >> 1) * 64, wn = (wave & 1) * 64;
  const int m0 = blockIdx.x * 128, n0 = blockIdx.y * 128;
  f32x4 acc[4][4] = {};
  for (int k0 = 0; k0 < 768; k0 += 64) {
    __syncthreads();
    #pragma unroll
    for (int j = 0; j < 4; ++j) {
      const int seg = wave * 4 + j;
      const int gr = seg * 8 + (lane >> 3), gc = (lane & 7) << 3;
      gld16(A + (m0 + gr) * 768 + k0 + gc, As + seg * 512);
      gld16(Bw + (n0 + gr) * 768 + k0 + gc, Bs + seg * 512);
    }
    __syncthreads();
    #pragma unroll
    for (int ks = 0; ks < 2; ++ks) {
      f16x8 af[4], bf[4];
      const int p = ((ks * 4 + hi) ^ (lo & 7)) << 3;
      #pragma unroll
      for (int t = 0; t < 4; ++t) {
        af[t] = *(const f16x8*)(As + (wm + t * 16 + lo) * 64 + p);
        bf[t] = *(const f16x8*)(Bs + (wn + t * 16 + lo) * 64 + p);
      }
      #pragma unroll
      for (int mt = 0; mt < 4; ++mt)
        #pragma unroll
        for (int nt = 0; nt < 4; ++nt)
          acc[mt][nt] = MFMA16(af[mt], bf[nt], acc[mt][nt]);
    }
  }
  // epilogue: C/D layout col=lane&15 (n), row=(lane>>4)*4+i (m)
  const int b = m0 >> 10;
  const int nrbase = (m0 & 1023) + wm;
  #pragma unroll
  for (int nt = 0; nt < 4; ++nt) {
    const int n = n0 + wn + nt * 16 + lo;
    if (n < 1728) {   // wave-uniform: 16-wide n-group never crosses a 576 boundary
      const float bv = bias[n];
      const int t3 = n / 576;
      const int rem = n - t3 * 576;
      const int hh = rem >> 6, d = rem & 63;
      const int bh16 = (b * 9 + hh) << 16;
      if (t3 == 2) {
        // V transposed + swizzled: element (d, t): chunk c=t>>3, pos=(c&~7)|((c^d)&7)
        _Float16* dv = Vt + bh16 + d * 1024;
        #pragma unroll
        for (int mt = 0; mt < 4; ++mt) {
          const int nr = nrbase + mt * 16 + hi * 4;
          const int c = nr >> 3;
          const int pos = (c & ~7) | ((c ^ d) & 7);
          union { f16x4 v; h16x2 h[2]; } u;
          u.h[0] = __builtin_amdgcn_cvt_pkrtz(acc[mt][nt][0] + bv, acc[mt][nt][1] + bv);
          u.h[1] = __builtin_amdgcn_cvt_pkrtz(acc[mt][nt][2] + bv, acc[mt][nt][3] + bv);
          *(f16x4*)(dv + pos * 8 + (nr & 7)) = u.v;
        }
      } else if (t3 == 1) {
        // K swizzled: element (t, d) at t*64 + ((d>>3 ^ (t&7))<<3) + (d&7)
        _Float16* dk = Ko + bh16;
        const int ch = d >> 3, dl = d & 7;
        #pragma unroll
        for (int mt = 0; mt < 4; ++mt) {
          const int nr = nrbase + mt * 16 + hi * 4;
          #pragma unroll
          for (int i = 0; i < 4; ++i) {
            const int t = nr + i;
            dk[t * 64 + ((ch ^ (t & 7)) << 3) + dl] = (_Float16)(acc[mt][nt][i] + bv);
          }
        }
      } else {
        _Float16* dq = Qo + bh16 + d;   // Q plain row-major
        #pragma unroll
        for (int mt = 0; mt < 4; ++mt) {
          const int nr = nrbase + mt * 16 + hi * 4;
          #pragma unroll
          for (int i = 0; i < 4; ++i)
            dq[(nr + i) * 64] = (_Float16)(acc[mt][nt][i] + bv);
        }
      }
    }
  }
}

// ---------------------------------------------------------------- flash attention
// S^T = K·Q^T, O^T = V^T·P^T.  64 q rows/block, K-tile 128.
// LDS: Ks[128x64] (aliased by per-wave Ps after S-read barrier) + Vts[64x128] = 32 KB.
__global__ __launch_bounds__(256, 4) void attn_fused(const _Float16* __restrict__ Qg,
                                                     const _Float16* __restrict__ Kg,
                                                     const _Float16* __restrict__ Vtg,
                                                     _Float16* __restrict__ Og) {
  __shared__ __align__(16) _Float16 Ks[128 * 64];
  __shared__ __align__(16) _Float16 Vts[64 * 128];
  const int tid = threadIdx.x;
  const int wave = tid >> 6, lane = tid & 63;
  const int lo = lane & 15, hi = lane >> 4;
  const int bh = blockIdx.x;
  const int q0 = blockIdx.y * 64;
  const _Float16* Qp  = Qg + (bh << 16);
  const _Float16* Kp  = Kg + (bh << 16);
  const _Float16* Vtp = Vtg + (bh << 16);

  // stage Q (64x64, plain global) into Ks region, xor-swizzled
  #pragma unroll
  for (int it = 0; it < 2; ++it) {
    const int c = it * 256 + tid;
    const int row = c >> 3, ch = c & 7;
    *(uint4*)(Ks + row * 64 + ((ch ^ (row & 7)) << 3)) =
        *(const uint4*)(Qp + (q0 + row) * 64 + ch * 8);
  }
  __syncthreads();
  f16x8 qf[2];
  #pragma unroll
  for (int ks = 0; ks < 2; ++ks)
    qf[ks] = *(const f16x8*)(Ks + (wave * 16 + lo) * 64 + (((ks * 4 + hi) ^ (lo & 7)) << 3));

  _Float16* Ps = Ks + wave * 2048;  // 16q x 128t, stride 128, xor-swizzled
  float m_run = -1e30f, l_run = 0.f;
  f32x4 accO[4] = {};
  const float cs = 0.125f * 1.44269504f;  // HD^-0.5 * log2(e)

  for (int t0 = 0; t0 < 1024; t0 += 128) {
    __syncthreads();  // prev PV reads of Ps(=Ks)/Vts done; iter0: qf loaded
    #pragma unroll
    for (int j = 0; j < 4; ++j) {
      const int seg = wave * 4 + j;
      gld16(Kp + (t0 + seg * 8 + (lane >> 3)) * 64 + ((lane & 7) << 3), Ks + seg * 512);
      gld16(Vtp + (seg * 4 + (lane >> 4)) * 1024 + t0 + ((lane & 15) << 3), Vts + seg * 512);
    }
    __syncthreads();  // DMA drained (vmcnt(0) before barrier)

    // S^T: C layout col=lo=q, row=hi*4+i (+16*tt) = t
    f32x4 sacc[8] = {};
    #pragma unroll
    for (int tt = 0; tt < 8; ++tt)
      #pragma unroll
      for (int ks = 0; ks < 2; ++ks) {
        const f16x8 kf = *(const f16x8*)(Ks + (tt * 16 + lo) * 64 + (((ks * 4 + hi) ^ (lo & 7)) << 3));
        sacc[tt] = MFMA16(kf, qf[ks], sacc[tt]);
      }
    __syncthreads();  // all waves done reading Ks before Ps overwrites it

    float rmax = -1e30f;
    #pragma unroll
    for (int tt = 0; tt < 8; ++tt)
      rmax = fmaxf(rmax, fmaxf(fmaxf(sacc[tt][0], sacc[tt][1]), fmaxf(sacc[tt][2], sacc[tt][3])));
    rmax = fmaxf(rmax, __shfl_xor(rmax, 16, 64));
    rmax = fmaxf(rmax, __shfl_xor(rmax, 32, 64));
    const float mnew = fmaxf(m_run, rmax * cs);
    const float alpha = __builtin_amdgcn_exp2f(m_run - mnew);
    float rsum = 0.f;
    #pragma unroll
    for (int tt = 0; tt < 8; ++tt) {
      const float p0 = __builtin_amdgcn_exp2f(fmaf(sacc[tt][0], cs, -mnew));
      const float p1 = __builtin_amdgcn_exp2f(fmaf(sacc[tt][1], cs, -mnew));
      const float p2 = __builtin_amdgcn_exp2f(fmaf(sacc[tt][2], cs, -mnew));
      const float p3 = __builtin_amdgcn_exp2f(fmaf(sacc[tt][3], cs, -mnew));
      rsum += (p0 + p1) + (p2 + p3);
      union { f16x4 v; h16x2 h[2]; } u;
      u.h[0] = __builtin_amdgcn_cvt_pkrtz(p0, p1);
      u.h[1] = __builtin_amdgcn_cvt_pkrtz(p2, p3);
      const int c = 2 * tt + (hi >> 1);
      *(f16x4*)(Ps + lo * 128 + (((c & 8) | ((c ^ lo) & 7)) << 3) + ((hi & 1) << 2)) = u.v;
    }
    rsum += __shfl_xor(rsum, 16, 64);
    rsum += __shfl_xor(rsum, 32, 64);
    l_run = l_run * alpha + rsum;
    m_run = mnew;
    #pragma unroll
    for (int dt = 0; dt < 4; ++dt) accO[dt] *= alpha;

    // O^T += V^T · P^T (Ps wave-private: no barrier before reads)
    #pragma unroll
    for (int ks2 = 0; ks2 < 4; ++ks2) {
      const int c = 4 * ks2 + hi;
      const f16x8 pf = *(const f16x8*)(Ps + lo * 128 + (((c & 8) | ((c ^ lo) & 7)) << 3));
      #pragma unroll
      for (int dt = 0; dt < 4; ++dt) {
        const int dd = dt * 16 + lo;
        const f16x8 vf = *(const f16x8*)(Vts + dd * 128 + (((c & 8) | ((c ^ dd) & 7)) << 3));
        accO[dt] = MFMA16(vf, pf, accO[dt]);
      }
    }
  }
  // O^T C layout: col=lo=q, row=hi*4+i (+16*dt) = d. Write Oh [16384,576] swizzled.
  const float inv = 1.f / l_run;
  const int b = bh / 9, hh = bh - b * 9;
  const int rq = (b << 10) + q0 + wave * 16 + lo;
  #pragma unroll
  for (int dt = 0; dt < 4; ++dt) {
    union { f16x4 v; h16x2 h[2]; } u;
    u.h[0] = __builtin_amdgcn_cvt_pkrtz(accO[dt][0] * inv, accO[dt][1] * inv);
    u.h[1] = __builtin_amdgcn_cvt_pkrtz(accO[dt][2] * inv, accO[dt][3] * inv);
    const int c = hh * 8 + dt * 2 + (hi >> 1);
    const int pos = (c & ~7) | ((c ^ rq) & 7);
    *(f16x4*)(Og + rq * 576 + pos * 8 + ((hi & 1) << 2)) = u.v;
  }
}

// ---------------------------------------------------------------- GEMM3: out = O @ proj_w^T + b (fp32 out)
__global__ __launch_bounds__(256, 4) void gemm3_proj(const _Float16* __restrict__ A,
                                                     const _Float16* __restrict__ Bw,
                                                     const float* __restrict__ bias,
                                                     float* __restrict__ out) {
  __shared__ __align__(16) _Float16 As[128 * 64];
  __shared__ __align__(16) _Float16 Bs[128 * 64];
  const int tid = threadIdx.x;
  const int wave = tid >> 6, lane = tid & 63;
  const int lo = lane & 15, hi = lane >> 4;
  const int wm = (wave >> 1) * 64, wn = (wave & 1) * 64;
  const int m0 = blockIdx.x * 128, n0 = blockIdx.y * 128;
  f32x4 acc[4][4] = {};
  for (int k0 = 0; k0 < 576; k0 += 64) {
    __syncthreads();
    #pragma unroll
    for (int j = 0; j < 4; ++j) {
      const int seg = wave * 4 + j;
      const int gr = seg * 8 + (lane >> 3), gc = (lane & 7) << 3;
      gld16(A + (m0 + gr) * 576 + k0 + gc, As + seg * 512);
      gld16(Bw + (n0 + gr) * 576 + k0 + gc, Bs + seg * 512);
    }
    __syncthreads();
    #pragma unroll
    for (int ks = 0; ks < 2; ++ks) {
      f16x8 af[4], bf[4];
      const int p = ((ks * 4 + hi) ^ (lo & 7)) << 3;
      #pragma unroll
      for (int t = 0; t < 4; ++t) {
        af[t] = *(const f16x8*)(As + (wm + t * 16 + lo) * 64 + p);
        bf[t] = *(const f16x8*)(Bs + (wn + t * 16 + lo) * 64 + p);
      }
      #pragma unroll
      for (int mt = 0; mt < 4; ++mt)
        #pragma unroll
        for (int nt = 0; nt < 4; ++nt)
          acc[mt][nt] = MFMA16(af[mt], bf[nt], acc[mt][nt]);
    }
  }
  #pragma unroll
  for (int nt = 0; nt < 4; ++nt) {
    const int n = n0 + wn + nt * 16 + lo;
    const float bv = bias[n];
    #pragma unroll
    for (int mt = 0; mt < 4; ++mt) {
      const int mrow = m0 + wm + mt * 16 + hi * 4;
      #pragma unroll
      for (int i = 0; i < 4; ++i)
        out[(mrow + i) * 768 + n] = acc[mt][nt][i] + bv;
    }
  }
}

// ---------------------------------------------------------------- launch
extern "C" void kernel_launch(void* const* d_in, const int* in_sizes, int n_in,
                              void* d_out, int out_size, void* d_ws, size_t ws_size,
                              hipStream_t stream) {
  const float* x      = (const float*)d_in[0];
  const float* qkv_w  = (const float*)d_in[1];
  const float* qkv_b  = (const float*)d_in[2];
  const float* proj_w = (const float*)d_in[3];
  const float* proj_b = (const float*)d_in[4];
  float* out = (float*)d_out;

  char* ws = (char*)d_ws;
  _Float16* x16 = (_Float16*)(ws + 0);          // 16384*768*2  swz
  _Float16* w1p = (_Float16*)(ws + 25165824);   // 1792*768*2   swz, rows>=1728 zero
  _Float16* w2h = (_Float16*)(ws + 27918336);   // 768*576*2    swz
  _Float16* Qh  = (_Float16*)(ws + 28803072);   // [bh][1024][64] plain
  _Float16* Kh  = (_Float16*)(ws + 47677440);   // [bh][1024][64] swz
  _Float16* Vth = (_Float16*)(ws + 66551808);   // [bh][64][1024] transposed swz
  _Float16* Oh  = (_Float16*)(ws + 85426176);   // [16384][576] swz

  cvt_swz<<<6144, 256, 0, stream>>>(x, x16, 16384, 96, 16384 * 96);
  cvt_swz<<<672, 256, 0, stream>>>(qkv_w, w1p, 1728, 96, 1792 * 96);
  cvt_swz<<<216, 256, 0, stream>>>(proj_w, w2h, 768, 72, 768 * 72);
  gemm1_qkv<<<dim3(128, 14), 256, 0, stream>>>(x16, w1p, qkv_b, Qh, Kh, Vth);
  attn_fused<<<dim3(144, 16), 256, 0, stream>>>(Qh, Kh, Vth, Oh);
  gemm3_proj<<<dim3(128, 6), 256, 0, stream>>>(Oh, w2h, proj_b, out);
}